// Round 5
// baseline (322.370 us; speedup 1.0000x reference)
//
#include <hip/hip_runtime.h>
#include <hip/hip_fp16.h>
#include <math.h>

#define NN   128
#define PSTR 132          // pool stride (floats): 16B-aligned rows
#define NTH  512

// native-instruction softplus: max(x,0) + ln2 * log2(1 + 2^(-|x|*log2e))
__device__ __forceinline__ float sp_softplus(float x) {
    float p = __builtin_amdgcn_exp2f(fabsf(x) * -1.44269504f);
    float l = __builtin_amdgcn_logf(1.0f + p);
    return fmaxf(x, 0.0f) + 0.69314718f * l;
}
__device__ __forceinline__ float rdlane(float v, int l) {
    return __int_as_float(__builtin_amdgcn_readlane(__float_as_int(v), l));
}
__device__ __forceinline__ float rcpf(float x)  { return __builtin_amdgcn_rcpf(x); }
__device__ __forceinline__ float rsqf(float x)  { return __builtin_amdgcn_rsqf(x); }

// ONE block per CU (grid=256), TWO molecules interleaved per block.
// 8-wave block at 1 block/CU -> 2 waves/SIMD -> 256-VGPR cap: the 2x register
// state (DWh,Bg per molecule = 128 regs) fits without spill. Barriers cover
// both molecules (half the per-molecule barrier count); independent A/B chains
// provide the ILP that 1-block occupancy can't get from TLP.
__global__ void __launch_bounds__(NTH, 1)
ts_gcn_kernel(const float* __restrict__ edge_pred,
              const int*   __restrict__ adj,
              const float* __restrict__ d_init,
              const float* __restrict__ u_init,
              const float* __restrict__ x_noise,
              float* __restrict__ out)
{
    __shared__ __align__(16) float poolA[NN * PSTR];   // 67.6 KB
    __shared__ __align__(16) float poolB[NN * PSTR];   // 67.6 KB
    __shared__ unsigned maskbA[512], maskbB[512];      // 4 KB
    __shared__ int cMA, cN0A, cMB, cN0B;

    // aliases (live only after staging passes are dead)
    float* scr0A = poolA;          float* scr0B = poolB;
    float* scr1A = poolA + 512;    float* scr1B = poolB + 512;
    float* scr2A = poolA + 1024;   float* scr2B = poolB + 1024;
    float* XxA   = poolA + 1536;   float* XxB   = poolB + 1536;
    float* XyA   = poolA + 1664;   float* XyB   = poolB + 1664;
    float* XzA   = poolA + 1792;   float* XzB   = poolB + 1792;
    float* rsA   = poolA + 1920;   float* rsB   = poolB + 1920;

    const int bA   = blockIdx.x * 2;
    const int bB   = bA + 1;
    const int t    = threadIdx.x;
    const int lane = t & 63;
    const int i    = t & 127;      // owned row
    const int q    = t >> 7;       // column quarter
    const int jb   = q * 32;
    const int lsel = jb & 63;
    const int hi6  = (t >> 6) & 1;

    const float dini = d_init[0];
    if (t == 0) { cMA = 0; cN0A = 0; cMB = 0; cN0B = 0; }

    // ---------------- Pass A: stage adj (both molecules), build mask bitmaps ----------
    const int4* adjA4 = (const int4*)(adj + (size_t)bA * 16384);
    const int4* adjB4 = (const int4*)(adj + (size_t)bB * 16384);
    #pragma unroll 2
    for (int k = 0; k < 8; ++k) {
        int e4 = t + k * 512;
        int4 vA = adjA4[e4];
        int4 vB = adjB4[e4];
        int ii = e4 >> 5, jj = (e4 & 31) * 4;
        float* pA = &poolA[ii * PSTR + jj];
        float* pB = &poolB[ii * PSTR + jj];
        pA[0] = __int_as_float(vA.x); pA[1] = __int_as_float(vA.y);
        pA[2] = __int_as_float(vA.z); pA[3] = __int_as_float(vA.w);
        pB[0] = __int_as_float(vB.x); pB[1] = __int_as_float(vB.y);
        pB[2] = __int_as_float(vB.z); pB[3] = __int_as_float(vB.w);
    }
    __syncthreads();
    unsigned mwA = 0, mwB = 0;
    #pragma unroll
    for (int k = 0; k < 32; ++k) {
        int j = jb + k;
        int aA = __float_as_int(poolA[i * PSTR + j]) | __float_as_int(poolA[j * PSTR + i]);
        int aB = __float_as_int(poolB[i * PSTR + j]) | __float_as_int(poolB[j * PSTR + i]);
        if (aA != 0 && i != j) mwA |= (1u << k);
        if (aB != 0 && i != j) mwB |= (1u << k);
    }
    maskbA[i * 4 + q] = mwA;
    maskbB[i * 4 + q] = mwB;
    int cmA = __popc(mwA), cmB = __popc(mwB);
    #pragma unroll
    for (int off = 32; off; off >>= 1) { cmA += __shfl_xor(cmA, off); cmB += __shfl_xor(cmB, off); }
    if (lane == 0) { atomicAdd(&cMA, cmA); atomicAdd(&cMB, cmB); }
    if (i == 0)    { atomicAdd(&cN0A, __popc(mwA)); atomicAdd(&cN0B, __popc(mwB)); }
    __syncthreads();

    // ---------------- Pass B: stage ep.ch0 (both) -> D ----------------
    const float4* epA4 = (const float4*)(edge_pred + (size_t)bA * 32768);
    const float4* epB4 = (const float4*)(edge_pred + (size_t)bB * 32768);
    #pragma unroll 2
    for (int k = 0; k < 16; ++k) {
        int e2 = t + k * 512;
        float4 vA = epA4[e2];
        float4 vB = epB4[e2];
        int ii = e2 >> 6, jj = (e2 & 63) * 2;
        *(float2*)&poolA[ii * PSTR + jj] = make_float2(vA.x, vA.z);
        *(float2*)&poolB[ii * PSTR + jj] = make_float2(vB.x, vB.z);
    }
    __syncthreads();
    float    DfA[32], DfB[32];
    unsigned DWhA[32], DWhB[32];       // lo16 = D half, hi16 = W half
    #pragma unroll
    for (int k = 0; k < 32; ++k) {
        int j = jb + k;
        float sA = poolA[i * PSTR + j] + poolA[j * PSTR + i];
        float sB = poolB[i * PSTR + j] + poolB[j * PSTR + i];
        float dA = ((mwA >> k) & 1) ? sp_softplus(dini + sA) : 0.f;
        float dB = ((mwB >> k) & 1) ? sp_softplus(dini + sB) : 0.f;
        DfA[k] = dA; DWhA[k] = (unsigned)__half_as_ushort(__float2half_rn(dA));
        DfB[k] = dB; DWhB[k] = (unsigned)__half_as_ushort(__float2half_rn(dB));
    }
    __syncthreads();           // pool(ep.x) reads done -> scr writable

    // ---------------- Row sums of D^2 + grand means ----------------
    float rpA = 0.f, rpB = 0.f;
    #pragma unroll
    for (int k = 0; k < 32; ++k) { rpA = fmaf(DfA[k], DfA[k], rpA); rpB = fmaf(DfB[k], DfB[k], rpB); }
    scr0A[t] = rpA; scr0B[t] = rpB;
    __syncthreads();
    if (t < NN) {
        rsA[t] = (scr0A[t] + scr0A[t + 128]) + (scr0A[t + 256] + scr0A[t + 384]);
    } else if (t < 256) {
        int tt = t - 128;
        rsB[tt] = (scr0B[tt] + scr0B[tt + 128]) + (scr0B[tt + 256] + scr0B[tt + 384]);
    }
    __syncthreads();
    float mtA = rsA[lane] + rsA[lane + 64];
    float mtB = rsB[lane] + rsB[lane + 64];
    #pragma unroll
    for (int off = 32; off; off >>= 1) { mtA += __shfl_xor(mtA, off); mtB += __shfl_xor(mtB, off); }

    const float invNA  = 1.0f / (float)(1 + cN0A);
    const float invNB  = 1.0f / (float)(1 + cN0B);
    const float MinvA  = 1.0f / (float)(128 + cMA);
    const float MinvB  = 1.0f / (float)(128 + cMB);
    const float cmeanA = mtA * invNA * invNA;
    const float cmeanB = mtB * invNB * invNB;

    // ---------------- Gram matrices into registers (Df dies here) ----------------
    const float riA = rsA[i], riB = rsB[i];
    float BgA[32], BgB[32];
    #pragma unroll
    for (int k = 0; k < 32; ++k) {
        int j = jb + k;
        float dA = DfA[k];
        float vA = -0.5f * (dA * dA - riA * invNA - rsA[j] * invNA + cmeanA);
        BgA[k] = (((mwA >> k) & 1) || (i == j)) ? vA : 0.f;
        float dB = DfB[k];
        float vB = -0.5f * (dB * dB - riB * invNB - rsB[j] * invNB + cmeanB);
        BgB[k] = (((mwB >> k) & 1) || (i == j)) ? vB : 0.f;
    }
    __syncthreads();           // rs reads done -> pool fully writable

    // ---------------- Pass C: stage ep.ch1 (both) -> W ----------------
    #pragma unroll 2
    for (int k = 0; k < 16; ++k) {
        int e2 = t + k * 512;
        float4 vA = epA4[e2];
        float4 vB = epB4[e2];
        int ii = e2 >> 6, jj = (e2 & 63) * 2;
        *(float2*)&poolA[ii * PSTR + jj] = make_float2(vA.y, vA.w);
        *(float2*)&poolB[ii * PSTR + jj] = make_float2(vB.y, vB.w);
    }
    __syncthreads();
    #pragma unroll
    for (int k = 0; k < 32; ++k) {
        int j = jb + k;
        float sA = poolA[i * PSTR + j] + poolA[j * PSTR + i];
        float sB = poolB[i * PSTR + j] + poolB[j * PSTR + i];
        float wA = ((mwA >> k) & 1) ? sp_softplus(dini + sA) : 0.f;
        float wB = ((mwB >> k) & 1) ? sp_softplus(dini + sB) : 0.f;
        DWhA[k] |= ((unsigned)__half_as_ushort(__float2half_rn(wA))) << 16;
        DWhB[k] |= ((unsigned)__half_as_ushort(__float2half_rn(wB))) << 16;
    }
    __syncthreads();           // staging dead; scr ping-pong live

    // ---------------- Power iteration: 3 ranks x 10 steps, 1 barrier/step --------------
    const float* ubA = u_init  + (size_t)bA * 384;
    const float* ubB = u_init  + (size_t)bB * 384;
    const float* xbA = x_noise + (size_t)bA * 384;
    const float* xbB = x_noise + (size_t)bB * 384;

    #pragma unroll 1
    for (int kx = 0; kx < 3; ++kx) {
        float uloA = ubA[lane * 3 + kx], uhiA = ubA[(lane + 64) * 3 + kx];
        float uloB = ubB[lane * 3 + kx], uhiB = ubB[(lane + 64) * 3 + kx];
        float* rdA = scr0A; float* wrA = scr1A;
        float* rdB = scr0B; float* wrB = scr1B;
        #pragma unroll 1
        for (int s = 0; s < 10; ++s) {
            if (s) {
                uloA = (rdA[lane]      + rdA[lane + 128]) + (rdA[lane + 256] + rdA[lane + 384]);
                uhiA = (rdA[lane + 64] + rdA[lane + 192]) + (rdA[lane + 320] + rdA[lane + 448]);
                uloB = (rdB[lane]      + rdB[lane + 128]) + (rdB[lane + 256] + rdB[lane + 384]);
                uhiB = (rdB[lane + 64] + rdB[lane + 192]) + (rdB[lane + 320] + rdB[lane + 448]);
            }
            float n2A = fmaf(uloA, uloA, uhiA * uhiA);
            float n2B = fmaf(uloB, uloB, uhiB * uhiB);
            #pragma unroll
            for (int off = 32; off; off >>= 1) { n2A += __shfl_xor(n2A, off); n2B += __shfl_xor(n2B, off); }
            float invA = rcpf(fmaxf(sqrtf(n2A), 0.001f));
            float invB = rcpf(fmaxf(sqrtf(n2B), 0.001f));
            float uselA = (q < 2) ? uloA : uhiA;
            float uselB = (q < 2) ? uloB : uhiB;
            float a0A = 0.f, a1A = 0.f, a0B = 0.f, a1B = 0.f;
            #pragma unroll
            for (int k = 0; k < 16; ++k) {
                a0A = fmaf(BgA[k],      rdlane(uselA, lsel + k),      a0A);
                a1A = fmaf(BgA[k + 16], rdlane(uselA, lsel + k + 16), a1A);
                a0B = fmaf(BgB[k],      rdlane(uselB, lsel + k),      a0B);
                a1B = fmaf(BgB[k + 16], rdlane(uselB, lsel + k + 16), a1B);
            }
            wrA[t] = (a0A + a1A) * invA;
            wrB[t] = (a0B + a1B) * invB;
            __syncthreads();
            float* tp;
            tp = rdA; rdA = wrA; wrA = tp;
            tp = rdB; rdB = wrB; wrB = tp;
        }
        float ulo2A = (rdA[lane]      + rdA[lane + 128]) + (rdA[lane + 256] + rdA[lane + 384]);
        float uhi2A = (rdA[lane + 64] + rdA[lane + 192]) + (rdA[lane + 320] + rdA[lane + 448]);
        float ulo2B = (rdB[lane]      + rdB[lane + 128]) + (rdB[lane + 256] + rdB[lane + 384]);
        float uhi2B = (rdB[lane + 64] + rdB[lane + 192]) + (rdB[lane + 320] + rdB[lane + 448]);
        float e2A = fmaf(ulo2A, ulo2A, uhi2A * uhi2A);
        float e2B = fmaf(ulo2B, ulo2B, uhi2B * uhi2B);
        #pragma unroll
        for (int off = 32; off; off >>= 1) { e2A += __shfl_xor(e2A, off); e2B += __shfl_xor(e2B, off); }
        float escA = rsqf(sqrtf(e2A + 0.01f));           // (eig_sq+0.01)^-0.25
        float escB = rsqf(sqrtf(e2B + 0.01f));
        float ufiA  = (hi6 ? uhi2A : ulo2A) * escA;
        float ufiB  = (hi6 ? uhi2B : ulo2B) * escB;
        float usclA = ((q < 2) ? ulo2A : uhi2A) * escA;
        float usclB = ((q < 2) ? ulo2B : uhi2B) * escB;
        #pragma unroll
        for (int k = 0; k < 32; ++k) {
            BgA[k] = fmaf(-ufiA, rdlane(usclA, lsel + k), BgA[k]);
            BgB[k] = fmaf(-ufiB, rdlane(usclB, lsel + k), BgB[k]);
        }
        if (t < NN) {
            float* Xc = (kx == 0) ? XxA : (kx == 1) ? XyA : XzA;
            Xc[t] = ufiA + xbA[t * 3 + kx];
        } else if (t < 256) {
            int tt = t - 128;
            float* Xc = (kx == 0) ? XxB : (kx == 1) ? XyB : XzB;
            Xc[tt] = ufiB + xbB[tt * 3 + kx];
        }
        __syncthreads();
    }

    // ---------------- Gradient descent: 10 steps ----------------
    const float stepcA = 0.4f * MinvA;
    const float stepcB = 0.4f * MinvB;
    #pragma unroll 1
    for (int st = 0; st < 10; ++st) {
        float xixA = XxA[i], xiyA = XyA[i], xizA = XzA[i];
        float xixB = XxB[i], xiyB = XyB[i], xizB = XzB[i];
        float gxA = 0.f, gyA = 0.f, gzA = 0.f;
        float gxB = 0.f, gyB = 0.f, gzB = 0.f;
        #pragma unroll
        for (int g = 0; g < 8; ++g) {
            float4 vxA = *(const float4*)&XxA[jb + 4 * g];
            float4 vyA = *(const float4*)&XyA[jb + 4 * g];
            float4 vzA = *(const float4*)&XzA[jb + 4 * g];
            float4 vxB = *(const float4*)&XxB[jb + 4 * g];
            float4 vyB = *(const float4*)&XyB[jb + 4 * g];
            float4 vzB = *(const float4*)&XzB[jb + 4 * g];
            #pragma unroll
            for (int c = 0; c < 4; ++c) {
                int k = 4 * g + c;
                {
                    unsigned pw = DWhA[k];
                    float Dk = __half2float(__ushort_as_half((unsigned short)(pw & 0xffffu)));
                    float Wk = __half2float(__ushort_as_half((unsigned short)(pw >> 16)));
                    float jx = (c == 0) ? vxA.x : (c == 1) ? vxA.y : (c == 2) ? vxA.z : vxA.w;
                    float jy = (c == 0) ? vyA.x : (c == 1) ? vyA.y : (c == 2) ? vyA.z : vyA.w;
                    float jz = (c == 0) ? vzA.x : (c == 1) ? vzA.y : (c == 2) ? vzA.z : vzA.w;
                    float dx = xixA - jx, dy = xiyA - jy, dz = xizA - jz;
                    float d2 = fmaf(dx, dx, fmaf(dy, dy, fmaf(dz, dz, 0.01f)));
                    float rv = rcpf(sqrtf(d2));
                    float c2 = fmaf(Dk * rv, Wk, -Wk);
                    gxA = fmaf(c2, dx, gxA); gyA = fmaf(c2, dy, gyA); gzA = fmaf(c2, dz, gzA);
                }
                {
                    unsigned pw = DWhB[k];
                    float Dk = __half2float(__ushort_as_half((unsigned short)(pw & 0xffffu)));
                    float Wk = __half2float(__ushort_as_half((unsigned short)(pw >> 16)));
                    float jx = (c == 0) ? vxB.x : (c == 1) ? vxB.y : (c == 2) ? vxB.z : vxB.w;
                    float jy = (c == 0) ? vyB.x : (c == 1) ? vyB.y : (c == 2) ? vyB.z : vyB.w;
                    float jz = (c == 0) ? vzB.x : (c == 1) ? vzB.y : (c == 2) ? vzB.z : vzB.w;
                    float dx = xixB - jx, dy = xiyB - jy, dz = xizB - jz;
                    float d2 = fmaf(dx, dx, fmaf(dy, dy, fmaf(dz, dz, 0.01f)));
                    float rv = rcpf(sqrtf(d2));
                    float c2 = fmaf(Dk * rv, Wk, -Wk);
                    gxB = fmaf(c2, dx, gxB); gyB = fmaf(c2, dy, gyB); gzB = fmaf(c2, dz, gzB);
                }
            }
        }
        scr0A[t] = gxA; scr1A[t] = gyA; scr2A[t] = gzA;
        scr0B[t] = gxB; scr1B[t] = gyB; scr2B[t] = gzB;
        __syncthreads();
        float alpha = 0.1f + 4.9f * (float)(10 - st) * 0.1f;
        if (t < NN) {
            float sx = (scr0A[t] + scr0A[t + 128]) + (scr0A[t + 256] + scr0A[t + 384]);
            float sy = (scr1A[t] + scr1A[t + 128]) + (scr1A[t + 256] + scr1A[t + 384]);
            float sz = (scr2A[t] + scr2A[t + 128]) + (scr2A[t + 256] + scr2A[t + 384]);
            float dxv = sx * stepcA, dyv = sy * stepcA, dzv = sz * stepcA;
            float spd = sqrtf(fmaf(dxv, dxv, fmaf(dyv, dyv, fmaf(dzv, dzv, 0.001f))));
            float z  = fminf(spd * rcpf(alpha), 20.0f);
            float e  = __builtin_amdgcn_exp2f(z * 2.88539008f);
            float th = (e - 1.0f) * rcpf(e + 1.0f);
            float scl = alpha * th * rcpf(spd);
            XxA[t] = fmaf(dxv, scl, XxA[t]);
            XyA[t] = fmaf(dyv, scl, XyA[t]);
            XzA[t] = fmaf(dzv, scl, XzA[t]);
        } else if (t < 256) {
            int tt = t - 128;
            float sx = (scr0B[tt] + scr0B[tt + 128]) + (scr0B[tt + 256] + scr0B[tt + 384]);
            float sy = (scr1B[tt] + scr1B[tt + 128]) + (scr1B[tt + 256] + scr1B[tt + 384]);
            float sz = (scr2B[tt] + scr2B[tt + 128]) + (scr2B[tt + 256] + scr2B[tt + 384]);
            float dxv = sx * stepcB, dyv = sy * stepcB, dzv = sz * stepcB;
            float spd = sqrtf(fmaf(dxv, dxv, fmaf(dyv, dyv, fmaf(dzv, dzv, 0.001f))));
            float z  = fminf(spd * rcpf(alpha), 20.0f);
            float e  = __builtin_amdgcn_exp2f(z * 2.88539008f);
            float th = (e - 1.0f) * rcpf(e + 1.0f);
            float scl = alpha * th * rcpf(spd);
            XxB[tt] = fmaf(dxv, scl, XxB[tt]);
            XyB[tt] = fmaf(dyv, scl, XyB[tt]);
            XzB[tt] = fmaf(dzv, scl, XzB[tt]);
        }
        __syncthreads();
    }

    // ---------------- Output: mask * distances(X), both molecules ----------------
    float* obA = out + (size_t)bA * 16384;
    float* obB = out + (size_t)bB * 16384;
    #pragma unroll 2
    for (int k = 0; k < 8; ++k) {
        int e4 = t + k * 512;
        int ii = e4 >> 5, jjb = (e4 & 31) * 4;
        {
            float xix = XxA[ii], xiy = XyA[ii], xiz = XzA[ii];
            float4 vx = *(const float4*)&XxA[jjb];
            float4 vy = *(const float4*)&XyA[jjb];
            float4 vz = *(const float4*)&XzA[jjb];
            unsigned mw = maskbA[ii * 4 + (jjb >> 5)];
            float4 o;
            float dx, dy, dz, d2;
            dx = xix - vx.x; dy = xiy - vy.x; dz = xiz - vz.x;
            d2 = fmaf(dx, dx, fmaf(dy, dy, fmaf(dz, dz, 0.01f)));
            o.x = ((mw >> ((jjb + 0) & 31)) & 1) ? sqrtf(d2) : 0.f;
            dx = xix - vx.y; dy = xiy - vy.y; dz = xiz - vz.y;
            d2 = fmaf(dx, dx, fmaf(dy, dy, fmaf(dz, dz, 0.01f)));
            o.y = ((mw >> ((jjb + 1) & 31)) & 1) ? sqrtf(d2) : 0.f;
            dx = xix - vx.z; dy = xiy - vy.z; dz = xiz - vz.z;
            d2 = fmaf(dx, dx, fmaf(dy, dy, fmaf(dz, dz, 0.01f)));
            o.z = ((mw >> ((jjb + 2) & 31)) & 1) ? sqrtf(d2) : 0.f;
            dx = xix - vx.w; dy = xiy - vy.w; dz = xiz - vz.w;
            d2 = fmaf(dx, dx, fmaf(dy, dy, fmaf(dz, dz, 0.01f)));
            o.w = ((mw >> ((jjb + 3) & 31)) & 1) ? sqrtf(d2) : 0.f;
            ((float4*)obA)[e4] = o;
        }
        {
            float xix = XxB[ii], xiy = XyB[ii], xiz = XzB[ii];
            float4 vx = *(const float4*)&XxB[jjb];
            float4 vy = *(const float4*)&XyB[jjb];
            float4 vz = *(const float4*)&XzB[jjb];
            unsigned mw = maskbB[ii * 4 + (jjb >> 5)];
            float4 o;
            float dx, dy, dz, d2;
            dx = xix - vx.x; dy = xiy - vy.x; dz = xiz - vz.x;
            d2 = fmaf(dx, dx, fmaf(dy, dy, fmaf(dz, dz, 0.01f)));
            o.x = ((mw >> ((jjb + 0) & 31)) & 1) ? sqrtf(d2) : 0.f;
            dx = xix - vx.y; dy = xiy - vy.y; dz = xiz - vz.y;
            d2 = fmaf(dx, dx, fmaf(dy, dy, fmaf(dz, dz, 0.01f)));
            o.y = ((mw >> ((jjb + 1) & 31)) & 1) ? sqrtf(d2) : 0.f;
            dx = xix - vx.z; dy = xiy - vy.z; dz = xiz - vz.z;
            d2 = fmaf(dx, dx, fmaf(dy, dy, fmaf(dz, dz, 0.01f)));
            o.z = ((mw >> ((jjb + 2) & 31)) & 1) ? sqrtf(d2) : 0.f;
            dx = xix - vx.w; dy = xiy - vy.w; dz = xiz - vz.w;
            d2 = fmaf(dx, dx, fmaf(dy, dy, fmaf(dz, dz, 0.01f)));
            o.w = ((mw >> ((jjb + 3) & 31)) & 1) ? sqrtf(d2) : 0.f;
            ((float4*)obB)[e4] = o;
        }
    }
}

extern "C" void kernel_launch(void* const* d_in, const int* in_sizes, int n_in,
                              void* d_out, int out_size, void* d_ws, size_t ws_size,
                              hipStream_t stream) {
    const float* edge_pred = (const float*)d_in[0];
    const int*   adj       = (const int*)  d_in[1];
    const float* dinit     = (const float*)d_in[2];
    const float* u_init    = (const float*)d_in[3];
    const float* x_noise   = (const float*)d_in[4];
    float*       out       = (float*)d_out;

    ts_gcn_kernel<<<256, NTH, 0, stream>>>(edge_pred, adj, dinit, u_init, x_noise, out);
}

// Round 7
// 318.015 us; speedup vs baseline: 1.0137x; 1.0137x over previous
//
#include <hip/hip_runtime.h>
#include <hip/hip_fp16.h>
#include <math.h>

#define NN   128
#define PSTR 132          // pool stride (floats): 16B-aligned rows
#define NTH  256

// native-instruction softplus: max(x,0) + ln2 * log2(1 + 2^(-|x|*log2e))
__device__ __forceinline__ float sp_softplus(float x) {
    float p = __builtin_amdgcn_exp2f(fabsf(x) * -1.44269504f);
    float l = __builtin_amdgcn_logf(1.0f + p);
    return fmaxf(x, 0.0f) + 0.69314718f * l;
}
__device__ __forceinline__ float rdlane(float v, int l) {
    return __int_as_float(__builtin_amdgcn_readlane(__float_as_int(v), l));
}
__device__ __forceinline__ float rcpf(float x)  { return __builtin_amdgcn_rcpf(x); }
__device__ __forceinline__ float rsqf(float x)  { return __builtin_amdgcn_rsqf(x); }

// 256-thread blocks (4 waves), 1 molecule per block, grid=512 -> 2 blocks/CU.
// hipcc's default VGPR cap is 128 (launch_bounds can only tighten it — rounds
// 2-5 evidence); amdgpu_waves_per_eu(2,2) relaxes it to 256 so the 64-col
// per-thread state (DWh[64]+Bg[64]+Dfull[64] peak ~215) fits spill-free.
// 2 waves/EU x ~230 VGPR <= 512/SIMD pool; LDS 2 x ~70KB <= 160KB -> two
// co-resident blocks whose barrier stalls hide under each other's compute.
__global__ void __launch_bounds__(NTH) __attribute__((amdgpu_waves_per_eu(2, 2)))
ts_gcn_kernel(const float* __restrict__ edge_pred,
              const int*   __restrict__ adj,
              const float* __restrict__ d_init,
              const float* __restrict__ u_init,
              const float* __restrict__ x_noise,
              float* __restrict__ out)
{
    __shared__ __align__(16) float pool[NN * PSTR];  // 67.6 KB staging + aliases
    __shared__ unsigned maskb[512];                  // 128 rows x 4 words of 32 cols
    __shared__ int s_cntM, s_cntN0;

    // aliases (live only after the covering staging pass is dead)
    float* scrA = pool;            // [256]
    float* scrB = pool + 256;      // [256]
    float* scrC = pool + 512;      // [256]
    float* Xx   = pool + 768;      // [128] (16B-aligned)
    float* Xy   = pool + 896;      // [128]
    float* Xz   = pool + 1024;     // [128]
    float* r_s  = pool + 1152;     // [128] (dead before Pass C clobbers it)

    const int b    = blockIdx.x;
    const int t    = threadIdx.x;  // 0..255
    const int lane = t & 63;
    const int i    = t & 127;      // owned row
    const int q    = t >> 7;       // column half: 0 -> cols 0..63, 1 -> 64..127
    const int jb   = q * 64;
    const int hi6  = (t >> 6) & 1; // row i >= 64 ?

    const float dini = d_init[0];
    if (t == 0) { s_cntM = 0; s_cntN0 = 0; }

    // ---------------- Pass A: stage adj, build 64-bit mask ----------------
    const int4* adj4 = (const int4*)(adj + (size_t)b * 16384);
    #pragma unroll 4
    for (int k = 0; k < 16; ++k) {
        int e4 = t + k * 256;
        int4 v = adj4[e4];
        int ii = e4 >> 5, jj = (e4 & 31) * 4;
        float* p = &pool[ii * PSTR + jj];
        p[0] = __int_as_float(v.x); p[1] = __int_as_float(v.y);
        p[2] = __int_as_float(v.z); p[3] = __int_as_float(v.w);
    }
    __syncthreads();
    unsigned long long mw = 0;
    #pragma unroll
    for (int k = 0; k < 64; ++k) {
        int j = jb + k;
        int a = __float_as_int(pool[i * PSTR + j]) | __float_as_int(pool[j * PSTR + i]);
        if (a != 0 && i != j) mw |= (1ull << k);
    }
    maskb[i * 4 + q * 2]     = (unsigned)mw;
    maskb[i * 4 + q * 2 + 1] = (unsigned)(mw >> 32);
    int cm = __popcll(mw);
    #pragma unroll
    for (int off = 32; off; off >>= 1) cm += __shfl_xor(cm, off);
    if (lane == 0) atomicAdd(&s_cntM, cm);
    if (i == 0)    atomicAdd(&s_cntN0, __popcll(mw));   // row0 == col0 by symmetry
    __syncthreads();

    // ---------------- Pass B: stage ep.ch0 -> D ----------------
    const float4* ep4 = (const float4*)(edge_pred + (size_t)b * 32768);
    #pragma unroll 4
    for (int k = 0; k < 32; ++k) {
        int e2 = t + k * 256;
        float4 v = ep4[e2];
        int ii = e2 >> 6, jj = (e2 & 63) * 2;
        *(float2*)&pool[ii * PSTR + jj] = make_float2(v.x, v.z);
    }
    __syncthreads();
    float    Dfull[64];
    unsigned DWh[64];          // lo16 = D half, hi16 = W half
    #pragma unroll
    for (int k = 0; k < 64; ++k) {
        int j = jb + k;
        float s = pool[i * PSTR + j] + pool[j * PSTR + i];
        float d = ((mw >> k) & 1) ? sp_softplus(dini + s) : 0.f;
        Dfull[k] = d;
        DWh[k] = (unsigned)__half_as_ushort(__float2half_rn(d));
    }
    __syncthreads();           // pool(ep.x) reads done -> scrA writable

    // ---------------- Row sums of D^2 + grand mean ----------------
    float rp = 0.f;
    #pragma unroll
    for (int k = 0; k < 64; ++k) rp = fmaf(Dfull[k], Dfull[k], rp);
    scrA[t] = rp;
    __syncthreads();
    if (t < NN) r_s[t] = scrA[t] + scrA[t + 128];
    __syncthreads();
    float mt = r_s[lane] + r_s[lane + 64];
    #pragma unroll
    for (int off = 32; off; off >>= 1) mt += __shfl_xor(mt, off);

    const float Nmol  = (float)(1 + s_cntN0);
    const float Minv  = 1.0f / (float)(128 + s_cntM);
    const float invN  = 1.0f / Nmol;
    const float cmean = mt * invN * invN;

    // ---------------- Gram matrix into registers (Dfull dies here) ----------------
    const float ri = r_s[i];
    float Bg[64];
    #pragma unroll
    for (int k = 0; k < 64; ++k) {
        int j = jb + k;
        float dv = Dfull[k];
        float v  = -0.5f * (dv * dv - ri * invN - r_s[j] * invN + cmean);
        bool msk = ((mw >> k) & 1) || (i == j);
        Bg[k] = msk ? v : 0.f;
    }
    __syncthreads();           // r_s reads done -> pool fully writable

    // ---------------- Pass C: stage ep.ch1 -> W ----------------
    #pragma unroll 4
    for (int k = 0; k < 32; ++k) {
        int e2 = t + k * 256;
        float4 v = ep4[e2];
        int ii = e2 >> 6, jj = (e2 & 63) * 2;
        *(float2*)&pool[ii * PSTR + jj] = make_float2(v.y, v.w);
    }
    __syncthreads();
    #pragma unroll
    for (int k = 0; k < 64; ++k) {
        int j = jb + k;
        float s = pool[i * PSTR + j] + pool[j * PSTR + i];
        float w = ((mw >> k) & 1) ? sp_softplus(dini + s) : 0.f;
        DWh[k] |= ((unsigned)__half_as_ushort(__float2half_rn(w))) << 16;
    }
    __syncthreads();           // staging dead; scr ping-pong live

    // ---------------- Power iteration: 3 ranks x 10 steps, 1 barrier/step --------------
    // invariant: v_{s+1} = (A v_s) / max(||v_s||, 1e-3)  (scale commutes with A)
    const float* ub = u_init  + (size_t)b * 384;
    const float* xb = x_noise + (size_t)b * 384;

    #pragma unroll 1
    for (int kx = 0; kx < 3; ++kx) {
        float ulo = ub[lane * 3 + kx];          // v rows lane / lane+64
        float uhi = ub[(lane + 64) * 3 + kx];
        float* rd = scrA; float* wr = scrB;
        #pragma unroll 1
        for (int s = 0; s < 10; ++s) {
            if (s) {
                ulo = rd[lane]      + rd[lane + 128];
                uhi = rd[lane + 64] + rd[lane + 192];
            }
            float n2 = fmaf(ulo, ulo, uhi * uhi);
            #pragma unroll
            for (int off = 32; off; off >>= 1) n2 += __shfl_xor(n2, off);
            float inv = rcpf(fmaxf(sqrtf(n2), 0.001f));
            float usel = q ? uhi : ulo;          // wave-uniform half select
            float a0 = 0.f, a1 = 0.f;
            #pragma unroll
            for (int k = 0; k < 32; ++k) {
                a0 = fmaf(Bg[k],      rdlane(usel, k),      a0);
                a1 = fmaf(Bg[k + 32], rdlane(usel, k + 32), a1);
            }
            wr[t] = (a0 + a1) * inv;             // partial of v_{s+1} (2 per row)
            __syncthreads();
            float* tmp = rd; rd = wr; wr = tmp;
        }
        float ulo2 = rd[lane]      + rd[lane + 128];
        float uhi2 = rd[lane + 64] + rd[lane + 192];
        float e2 = fmaf(ulo2, ulo2, uhi2 * uhi2);
        #pragma unroll
        for (int off = 32; off; off >>= 1) e2 += __shfl_xor(e2, off);
        float esc  = rsqf(sqrtf(e2 + 0.01f));    // (eig_sq+0.01)^-0.25
        float ufi  = (hi6 ? uhi2 : ulo2) * esc;  // row i component
        float uscl = (q ? uhi2 : ulo2) * esc;
        #pragma unroll
        for (int k = 0; k < 64; ++k)
            Bg[k] = fmaf(-ufi, rdlane(uscl, k), Bg[k]);   // deflate
        if (t < NN) {
            float* Xc = (kx == 0) ? Xx : (kx == 1) ? Xy : Xz;
            Xc[t] = ufi + xb[t * 3 + kx];
        }
        __syncthreads();
    }

    // ---------------- Gradient descent: 10 steps ----------------
    // dx_i = (0.4/M) * sum_j W_ij (D_ij - DX_ij)/DX_ij * (x_i - x_j)
    const float stepc = 0.4f * Minv;
    #pragma unroll 1
    for (int st = 0; st < 10; ++st) {
        float xix = Xx[i], xiy = Xy[i], xiz = Xz[i];
        float gx = 0.f, gy = 0.f, gz = 0.f;
        #pragma unroll
        for (int g = 0; g < 16; ++g) {
            // wave-uniform float4 broadcasts: 3 ds_read_b128 per 4 columns
            float4 vx = *(const float4*)&Xx[jb + 4 * g];
            float4 vy = *(const float4*)&Xy[jb + 4 * g];
            float4 vz = *(const float4*)&Xz[jb + 4 * g];
            #pragma unroll
            for (int c = 0; c < 4; ++c) {
                int k = 4 * g + c;
                unsigned pw = DWh[k];
                float Dk = __half2float(__ushort_as_half((unsigned short)(pw & 0xffffu)));
                float Wk = __half2float(__ushort_as_half((unsigned short)(pw >> 16)));
                float jx = (c == 0) ? vx.x : (c == 1) ? vx.y : (c == 2) ? vx.z : vx.w;
                float jy = (c == 0) ? vy.x : (c == 1) ? vy.y : (c == 2) ? vy.z : vy.w;
                float jz = (c == 0) ? vz.x : (c == 1) ? vz.y : (c == 2) ? vz.z : vz.w;
                float dx = xix - jx, dy = xiy - jy, dz = xiz - jz;
                float d2 = fmaf(dx, dx, fmaf(dy, dy, fmaf(dz, dz, 0.01f)));
                float rv = rcpf(sqrtf(d2));
                float c2 = fmaf(Dk * rv, Wk, -Wk);       // W*(D/DX - 1)
                gx = fmaf(c2, dx, gx);
                gy = fmaf(c2, dy, gy);
                gz = fmaf(c2, dz, gz);
            }
        }
        scrA[t] = gx; scrB[t] = gy; scrC[t] = gz;
        __syncthreads();
        if (t < NN) {
            float sx = scrA[t] + scrA[t + 128];
            float sy = scrB[t] + scrB[t + 128];
            float sz = scrC[t] + scrC[t + 128];
            float dxv = sx * stepc, dyv = sy * stepc, dzv = sz * stepc;
            float spd = sqrtf(fmaf(dxv, dxv, fmaf(dyv, dyv, fmaf(dzv, dzv, 0.001f))));
            float alpha = 0.1f + 4.9f * (float)(10 - st) * 0.1f;
            // fast tanh: (e-1)/(e+1), e = exp(2z), z clamped
            float z  = fminf(spd * rcpf(alpha), 20.0f);
            float e  = __builtin_amdgcn_exp2f(z * 2.88539008f);
            float th = (e - 1.0f) * rcpf(e + 1.0f);
            float scl = alpha * th * rcpf(spd);
            Xx[t] = fmaf(dxv, scl, Xx[t]);
            Xy[t] = fmaf(dyv, scl, Xy[t]);
            Xz[t] = fmaf(dzv, scl, Xz[t]);
        }
        __syncthreads();
    }

    // ---------------- Output: mask * distances(X), float4 stores ----------------
    float* ob = out + (size_t)b * 16384;
    #pragma unroll 4
    for (int k = 0; k < 16; ++k) {
        int e4 = t + k * 256;
        int ii = e4 >> 5, jjb = (e4 & 31) * 4;
        float xix = Xx[ii], xiy = Xy[ii], xiz = Xz[ii];
        float4 vx = *(const float4*)&Xx[jjb];
        float4 vy = *(const float4*)&Xy[jjb];
        float4 vz = *(const float4*)&Xz[jjb];
        unsigned mwo = maskb[ii * 4 + (jjb >> 5)];
        float4 o;
        float dx, dy, dz, d2;
        dx = xix - vx.x; dy = xiy - vy.x; dz = xiz - vz.x;
        d2 = fmaf(dx, dx, fmaf(dy, dy, fmaf(dz, dz, 0.01f)));
        o.x = ((mwo >> ((jjb + 0) & 31)) & 1) ? sqrtf(d2) : 0.f;
        dx = xix - vx.y; dy = xiy - vy.y; dz = xiz - vz.y;
        d2 = fmaf(dx, dx, fmaf(dy, dy, fmaf(dz, dz, 0.01f)));
        o.y = ((mwo >> ((jjb + 1) & 31)) & 1) ? sqrtf(d2) : 0.f;
        dx = xix - vx.z; dy = xiy - vy.z; dz = xiz - vz.z;
        d2 = fmaf(dx, dx, fmaf(dy, dy, fmaf(dz, dz, 0.01f)));
        o.z = ((mwo >> ((jjb + 2) & 31)) & 1) ? sqrtf(d2) : 0.f;
        dx = xix - vx.w; dy = xiy - vy.w; dz = xiz - vz.w;
        d2 = fmaf(dx, dx, fmaf(dy, dy, fmaf(dz, dz, 0.01f)));
        o.w = ((mwo >> ((jjb + 3) & 31)) & 1) ? sqrtf(d2) : 0.f;
        ((float4*)ob)[e4] = o;
    }
}

extern "C" void kernel_launch(void* const* d_in, const int* in_sizes, int n_in,
                              void* d_out, int out_size, void* d_ws, size_t ws_size,
                              hipStream_t stream) {
    const float* edge_pred = (const float*)d_in[0];
    const int*   adj       = (const int*)  d_in[1];
    const float* dinit     = (const float*)d_in[2];
    const float* u_init    = (const float*)d_in[3];
    const float* x_noise   = (const float*)d_in[4];
    float*       out       = (float*)d_out;

    ts_gcn_kernel<<<512, NTH, 0, stream>>>(edge_pred, adj, dinit, u_init, x_noise, out);
}

// Round 8
// 239.563 us; speedup vs baseline: 1.3457x; 1.3275x over previous
//
#include <hip/hip_runtime.h>
#include <math.h>

#define NN   128
#define PSTR 132          // pool stride (floats): 16B-aligned rows
#define NTH  512

// native-instruction softplus: max(x,0) + ln2 * log2(1 + 2^(-|x|*log2e))
__device__ __forceinline__ float sp_softplus(float x) {
    float p = __builtin_amdgcn_exp2f(fabsf(x) * -1.44269504f);
    float l = __builtin_amdgcn_logf(1.0f + p);
    return fmaxf(x, 0.0f) + 0.69314718f * l;
}
__device__ __forceinline__ float rcpf(float x)  { return __builtin_amdgcn_rcpf(x); }
__device__ __forceinline__ float rsqf(float x)  { return __builtin_amdgcn_rsqf(x); }

// 512-thread blocks, 1 molecule each, grid=512. VGPR target ~108 (fp32 state,
// round-1 evidence) < 128 -> 4 waves/SIMD fit register-wise; LDS 70KB -> two
// 8-wave blocks co-resident per CU (140KB < 160KB). 128-VGPR is a hard
// toolchain ceiling (rounds 2/5/7: every relax attempt ignored or spilled),
// so the block must simply fit UNDER it.
__global__ void __launch_bounds__(NTH)
ts_gcn_kernel(const float* __restrict__ edge_pred,
              const int*   __restrict__ adj,
              const float* __restrict__ d_init,
              const float* __restrict__ u_init,
              const float* __restrict__ x_noise,
              float* __restrict__ out)
{
    __shared__ __align__(16) float pool[NN * PSTR];  // 67.6 KB staging + aliases
    __shared__ unsigned maskb[512];
    __shared__ float nrm2[2];
    __shared__ int s_cntM, s_cntN0;

    // aliases (live only after the covering staging pass is dead)
    float* scrA = pool;            // [512]
    float* scrB = pool + 512;      // [512]
    float* scrC = pool + 1024;     // [512]
    float* Xx   = pool + 1536;     // [128] 16B-aligned
    float* Xy   = pool + 1664;     // [128]
    float* Xz   = pool + 1792;     // [128]
    float* u_s  = pool + 1920;     // [128]
    float* r_s  = pool + 2048;     // [128] (dead before Pass C)

    const int b    = blockIdx.x;
    const int t    = threadIdx.x;
    const int lane = t & 63;
    const int i    = t & 127;      // owned row
    const int q    = t >> 7;       // column quarter (wave-uniform)
    const int jb   = q * 32;

    const float dini = d_init[0];
    if (t == 0) { s_cntM = 0; s_cntN0 = 0; }

    // ---------------- Pass A: stage adj, build mask bitmap ----------------
    const int4* adj4 = (const int4*)(adj + (size_t)b * 16384);
    #pragma unroll 4
    for (int k = 0; k < 8; ++k) {
        int e4 = t + k * 512;
        int4 v = adj4[e4];
        int ii = e4 >> 5, jj = (e4 & 31) * 4;
        float* p = &pool[ii * PSTR + jj];
        p[0] = __int_as_float(v.x); p[1] = __int_as_float(v.y);
        p[2] = __int_as_float(v.z); p[3] = __int_as_float(v.w);
    }
    __syncthreads();
    unsigned mword = 0;
    #pragma unroll
    for (int k = 0; k < 32; ++k) {
        int j = jb + k;
        int a = __float_as_int(pool[i * PSTR + j]) | __float_as_int(pool[j * PSTR + i]);
        if (a != 0 && i != j) mword |= (1u << k);
    }
    maskb[i * 4 + q] = mword;
    int cm = __popc(mword);
    #pragma unroll
    for (int off = 32; off; off >>= 1) cm += __shfl_xor(cm, off);
    if (lane == 0) atomicAdd(&s_cntM, cm);
    if (i == 0)    atomicAdd(&s_cntN0, __popc(mword));  // row0 == col0 by symmetry
    __syncthreads();

    // ---------------- Pass B: stage ep.ch0 -> D (fp32 registers) ----------------
    const float4* ep4 = (const float4*)(edge_pred + (size_t)b * 32768);
    #pragma unroll 4
    for (int k = 0; k < 16; ++k) {
        int e2 = t + k * 512;
        float4 v = ep4[e2];
        int ii = e2 >> 6, jj = (e2 & 63) * 2;
        *(float2*)&pool[ii * PSTR + jj] = make_float2(v.x, v.z);
    }
    __syncthreads();
    float Dreg[32];
    #pragma unroll
    for (int k = 0; k < 32; ++k) {
        int j = jb + k;
        float s = pool[i * PSTR + j] + pool[j * PSTR + i];
        Dreg[k] = ((mword >> k) & 1) ? sp_softplus(dini + s) : 0.f;
    }
    __syncthreads();           // pool(ep.x) reads done -> scrA writable

    // ---------------- Row sums of D^2 + grand mean ----------------
    float rp = 0.f;
    #pragma unroll
    for (int k = 0; k < 32; ++k) rp = fmaf(Dreg[k], Dreg[k], rp);
    scrA[t] = rp;
    __syncthreads();
    if (t < NN)
        r_s[t] = (scrA[t] + scrA[t + 128]) + (scrA[t + 256] + scrA[t + 384]);
    __syncthreads();
    float mt = r_s[lane] + r_s[lane + 64];
    #pragma unroll
    for (int off = 32; off; off >>= 1) mt += __shfl_xor(mt, off);

    const float Minv  = 1.0f / (float)(128 + s_cntM);
    const float invN  = 1.0f / (float)(1 + s_cntN0);
    const float cmean = mt * invN * invN;

    // ---------------- Gram matrix into registers ----------------
    const float ri = r_s[i];
    float Bg[32];
    #pragma unroll
    for (int k = 0; k < 32; ++k) {
        int j = jb + k;
        float dv = Dreg[k];
        float v  = -0.5f * (dv * dv - ri * invN - r_s[j] * invN + cmean);
        bool msk = ((mword >> k) & 1) || (i == j);
        Bg[k] = msk ? v : 0.f;
    }
    __syncthreads();           // r_s dead -> pool fully writable

    // ---------------- Pass C: stage ep.ch1 -> W (fp32 registers) ----------------
    #pragma unroll 4
    for (int k = 0; k < 16; ++k) {
        int e2 = t + k * 512;
        float4 v = ep4[e2];
        int ii = e2 >> 6, jj = (e2 & 63) * 2;
        *(float2*)&pool[ii * PSTR + jj] = make_float2(v.y, v.w);
    }
    __syncthreads();
    float Wreg[32];
    #pragma unroll
    for (int k = 0; k < 32; ++k) {
        int j = jb + k;
        float s = pool[i * PSTR + j] + pool[j * PSTR + i];
        Wreg[k] = ((mword >> k) & 1) ? sp_softplus(dini + s) : 0.f;
    }
    __syncthreads();           // staging dead; scrA/u_s live

    // ---------------- Power iteration: 3 ranks x 10 steps ----------------
    // v_{s+1} = A v_s / max(||v_s||,1e-3): u in LDS (float4 broadcasts, no
    // readlane); norm via 2-wave butterfly published in nrm2[2].
    const float* ub = u_init  + (size_t)b * 384;
    const float* xb = x_noise + (size_t)b * 384;

    #pragma unroll 1
    for (int kx = 0; kx < 3; ++kx) {
        #pragma unroll 1
        for (int s = 0; s < 10; ++s) {
            if (t < NN) {   // waves 0,1 exactly
                float v = (s == 0) ? ub[t * 3 + kx]
                        : (scrA[t] + scrA[t + 128]) + (scrA[t + 256] + scrA[t + 384]);
                u_s[t] = v;
                float p2 = v * v;
                #pragma unroll
                for (int off = 32; off; off >>= 1) p2 += __shfl_xor(p2, off);
                if (lane == 0) nrm2[t >> 6] = p2;
            }
            __syncthreads();   // B1: u_s, nrm2 visible; scrA reads done
            float inv = rcpf(fmaxf(sqrtf(nrm2[0] + nrm2[1]), 0.001f));
            float a = 0.f;
            #pragma unroll
            for (int g = 0; g < 8; ++g) {
                float4 u4 = *(const float4*)&u_s[jb + 4 * g];
                a = fmaf(Bg[4*g    ], u4.x, a);
                a = fmaf(Bg[4*g + 1], u4.y, a);
                a = fmaf(Bg[4*g + 2], u4.z, a);
                a = fmaf(Bg[4*g + 3], u4.w, a);
            }
            scrA[t] = a * inv;
            __syncthreads();   // B2: new partials visible
        }
        // final v_10: magnitude matters (eig scaling)
        if (t < NN) {
            float v = (scrA[t] + scrA[t + 128]) + (scrA[t + 256] + scrA[t + 384]);
            u_s[t] = v;
            float p2 = v * v;
            #pragma unroll
            for (int off = 32; off; off >>= 1) p2 += __shfl_xor(p2, off);
            if (lane == 0) nrm2[t >> 6] = p2;
        }
        __syncthreads();       // B3
        float e2  = nrm2[0] + nrm2[1];
        float esc = rsqf(sqrtf(e2 + 0.01f));      // (eig_sq+0.01)^-0.25
        float c   = u_s[i] * esc * esc;           // row-i factor (scaled^2)
        #pragma unroll
        for (int g = 0; g < 8; ++g) {
            float4 u4 = *(const float4*)&u_s[jb + 4 * g];
            Bg[4*g    ] = fmaf(-c, u4.x, Bg[4*g    ]);
            Bg[4*g + 1] = fmaf(-c, u4.y, Bg[4*g + 1]);
            Bg[4*g + 2] = fmaf(-c, u4.z, Bg[4*g + 2]);
            Bg[4*g + 3] = fmaf(-c, u4.w, Bg[4*g + 3]);
        }
        if (t < NN) {
            float* Xc = (kx == 0) ? Xx : (kx == 1) ? Xy : Xz;
            Xc[t] = u_s[t] * esc + xb[t * 3 + kx];   // x0 = lowrank + noise
        }
        __syncthreads();       // B4: u_s reads done before next rank's writes
    }

    // ---------------- Gradient descent: 10 steps ----------------
    // dx_i = (0.4/M) * sum_j W_ij (D_ij - DX_ij)/DX_ij * (x_i - x_j)
    const float stepc = 0.4f * Minv;
    #pragma unroll 1
    for (int st = 0; st < 10; ++st) {
        float xix = Xx[i], xiy = Xy[i], xiz = Xz[i];
        float gx = 0.f, gy = 0.f, gz = 0.f;
        #pragma unroll
        for (int g = 0; g < 8; ++g) {
            float4 vx = *(const float4*)&Xx[jb + 4 * g];   // wave-uniform b128
            float4 vy = *(const float4*)&Xy[jb + 4 * g];
            float4 vz = *(const float4*)&Xz[jb + 4 * g];
            #pragma unroll
            for (int c = 0; c < 4; ++c) {
                int k = 4 * g + c;
                float jx = (c == 0) ? vx.x : (c == 1) ? vx.y : (c == 2) ? vx.z : vx.w;
                float jy = (c == 0) ? vy.x : (c == 1) ? vy.y : (c == 2) ? vy.z : vy.w;
                float jz = (c == 0) ? vz.x : (c == 1) ? vz.y : (c == 2) ? vz.z : vz.w;
                float dx = xix - jx, dy = xiy - jy, dz = xiz - jz;
                float d2 = fmaf(dx, dx, fmaf(dy, dy, fmaf(dz, dz, 0.01f)));
                float rv = rsqf(d2);                      // 1/DX
                float c2 = fmaf(Dreg[k] * rv, Wreg[k], -Wreg[k]);  // W*(D/DX-1)
                gx = fmaf(c2, dx, gx);
                gy = fmaf(c2, dy, gy);
                gz = fmaf(c2, dz, gz);
            }
        }
        scrA[t] = gx; scrB[t] = gy; scrC[t] = gz;
        __syncthreads();
        if (t < NN) {
            float sx = (scrA[t] + scrA[t + 128]) + (scrA[t + 256] + scrA[t + 384]);
            float sy = (scrB[t] + scrB[t + 128]) + (scrB[t + 256] + scrB[t + 384]);
            float sz = (scrC[t] + scrC[t + 128]) + (scrC[t + 256] + scrC[t + 384]);
            float dxv = sx * stepc, dyv = sy * stepc, dzv = sz * stepc;
            float spd = sqrtf(fmaf(dxv, dxv, fmaf(dyv, dyv, fmaf(dzv, dzv, 0.001f))));
            float alpha = 0.1f + 4.9f * (float)(10 - st) * 0.1f;
            // fast tanh: (e-1)/(e+1), e = exp(2z), z clamped
            float z  = fminf(spd * rcpf(alpha), 20.0f);
            float e  = __builtin_amdgcn_exp2f(z * 2.88539008f);
            float th = (e - 1.0f) * rcpf(e + 1.0f);
            float scl = alpha * th * rcpf(spd);
            Xx[t] = fmaf(dxv, scl, Xx[t]);
            Xy[t] = fmaf(dyv, scl, Xy[t]);
            Xz[t] = fmaf(dzv, scl, Xz[t]);
        }
        __syncthreads();
    }

    // ---------------- Output: mask * distances(X), float4 stores ----------------
    float* ob = out + (size_t)b * 16384;
    #pragma unroll
    for (int k = 0; k < 8; ++k) {
        int e4 = t + k * 512;
        int ii = e4 >> 5, jjb = (e4 & 31) * 4;
        float xix = Xx[ii], xiy = Xy[ii], xiz = Xz[ii];
        float4 vx = *(const float4*)&Xx[jjb];
        float4 vy = *(const float4*)&Xy[jjb];
        float4 vz = *(const float4*)&Xz[jjb];
        unsigned mw = maskb[ii * 4 + (jjb >> 5)];
        float4 o;
        float dx, dy, dz, d2;
        dx = xix - vx.x; dy = xiy - vy.x; dz = xiz - vz.x;
        d2 = fmaf(dx, dx, fmaf(dy, dy, fmaf(dz, dz, 0.01f)));
        o.x = ((mw >> ((jjb + 0) & 31)) & 1) ? sqrtf(d2) : 0.f;
        dx = xix - vx.y; dy = xiy - vy.y; dz = xiz - vz.y;
        d2 = fmaf(dx, dx, fmaf(dy, dy, fmaf(dz, dz, 0.01f)));
        o.y = ((mw >> ((jjb + 1) & 31)) & 1) ? sqrtf(d2) : 0.f;
        dx = xix - vx.z; dy = xiy - vy.z; dz = xiz - vz.z;
        d2 = fmaf(dx, dx, fmaf(dy, dy, fmaf(dz, dz, 0.01f)));
        o.z = ((mw >> ((jjb + 2) & 31)) & 1) ? sqrtf(d2) : 0.f;
        dx = xix - vx.w; dy = xiy - vy.w; dz = xiz - vz.w;
        d2 = fmaf(dx, dx, fmaf(dy, dy, fmaf(dz, dz, 0.01f)));
        o.w = ((mw >> ((jjb + 3) & 31)) & 1) ? sqrtf(d2) : 0.f;
        ((float4*)ob)[e4] = o;
    }
}

extern "C" void kernel_launch(void* const* d_in, const int* in_sizes, int n_in,
                              void* d_out, int out_size, void* d_ws, size_t ws_size,
                              hipStream_t stream) {
    const float* edge_pred = (const float*)d_in[0];
    const int*   adj       = (const int*)  d_in[1];
    const float* dinit     = (const float*)d_in[2];
    const float* u_init    = (const float*)d_in[3];
    const float* x_noise   = (const float*)d_in[4];
    float*       out       = (float*)d_out;

    ts_gcn_kernel<<<512, NTH, 0, stream>>>(edge_pred, adj, dinit, u_init, x_noise, out);
}

// Round 9
// 239.058 us; speedup vs baseline: 1.3485x; 1.0021x over previous
//
#include <hip/hip_runtime.h>
#include <hip/hip_fp16.h>
#include <math.h>

#define NN    128
#define PSTRH 134         // halves per row: 268B rows; 268/4=67 dwords, gcd(67,32)=1 -> spread banks
#define NTH   512

// native-instruction softplus: max(x,0) + ln2 * log2(1 + 2^(-|x|*log2e))
__device__ __forceinline__ float sp_softplus(float x) {
    float p = __builtin_amdgcn_exp2f(fabsf(x) * -1.44269504f);
    float l = __builtin_amdgcn_logf(1.0f + p);
    return fmaxf(x, 0.0f) + 0.69314718f * l;
}
__device__ __forceinline__ float rcpf(float x)  { return __builtin_amdgcn_rcpf(x); }
__device__ __forceinline__ float rsqf(float x)  { return __builtin_amdgcn_rsqf(x); }
__device__ __forceinline__ unsigned short f2h(float x) {
    return __half_as_ushort(__float2half_rn(x));
}
__device__ __forceinline__ float h2f(unsigned short h) {
    return __half2float(__ushort_as_half(h));
}

// Round-8 structure with the LDS block cut 70KB -> ~39KB (fp16 staging pool).
// Rationale: at VGPR=112, 2 blocks/CU fit the register file (448/SIMD <= 512)
// and nominal LDS (140KB <= 160KB) yet occupancy stayed 1 block/CU -> testable
// hypothesis that usable LDS for co-residency is ~128KB. At 39KB/block, two
// 8-wave blocks co-reside under any plausible cap; partner block hides the
// ~60% barrier/latency stall measured in round 8 (VALUBusy 40%, dur 145us).
__global__ void __launch_bounds__(NTH)
ts_gcn_kernel(const float* __restrict__ edge_pred,
              const int*   __restrict__ adj,
              const float* __restrict__ d_init,
              const float* __restrict__ u_init,
              const float* __restrict__ x_noise,
              float* __restrict__ out)
{
    __shared__ __align__(16) unsigned short poolh[NN * PSTRH]; // 34,304 B
    __shared__ unsigned maskb[512];                            // 2 KB
    __shared__ __align__(16) float Xx[NN], Xy[NN], Xz[NN];     // SoA coordinates
    __shared__ float u_s[NN], r_s[NN], nrm2[2];
    __shared__ int s_cntM, s_cntN0;

    // scratch aliases into poolh (live only after staging passes are dead)
    float* scrA = (float*)poolh;          // [512]
    float* scrB = (float*)poolh + 512;    // [512]
    float* scrC = (float*)poolh + 1024;   // [512]  (6KB <= 34.3KB pool)

    const int b    = blockIdx.x;
    const int t    = threadIdx.x;
    const int lane = t & 63;
    const int i    = t & 127;      // owned row
    const int q    = t >> 7;       // column quarter (wave-uniform)
    const int jb   = q * 32;

    const float dini = d_init[0];
    if (t == 0) { s_cntM = 0; s_cntN0 = 0; }

    // ---------------- Pass A: stage adj (u16), build mask bitmap ----------------
    const int4* adj4 = (const int4*)(adj + (size_t)b * 16384);
    #pragma unroll 4
    for (int k = 0; k < 8; ++k) {
        int e4 = t + k * 512;
        int4 v = adj4[e4];
        int ii = e4 >> 5, jj = (e4 & 31) * 4;
        ushort2 w0 = make_ushort2((unsigned short)v.x, (unsigned short)v.y);
        ushort2 w1 = make_ushort2((unsigned short)v.z, (unsigned short)v.w);
        *(ushort2*)&poolh[ii * PSTRH + jj]     = w0;
        *(ushort2*)&poolh[ii * PSTRH + jj + 2] = w1;
    }
    __syncthreads();
    unsigned mword = 0;
    #pragma unroll
    for (int k = 0; k < 32; ++k) {
        int j = jb + k;
        unsigned a = (unsigned)poolh[i * PSTRH + j] | (unsigned)poolh[j * PSTRH + i];
        if (a != 0 && i != j) mword |= (1u << k);
    }
    maskb[i * 4 + q] = mword;
    int cm = __popc(mword);
    #pragma unroll
    for (int off = 32; off; off >>= 1) cm += __shfl_xor(cm, off);
    if (lane == 0) atomicAdd(&s_cntM, cm);
    if (i == 0)    atomicAdd(&s_cntN0, __popc(mword));  // row0 == col0 by symmetry
    __syncthreads();

    // ---------------- Pass B: stage ep.ch0 (fp16) -> Dreg ----------------
    const float4* ep4 = (const float4*)(edge_pred + (size_t)b * 32768);
    #pragma unroll 4
    for (int k = 0; k < 16; ++k) {
        int e2 = t + k * 512;
        float4 v = ep4[e2];
        int ii = e2 >> 6, jj = (e2 & 63) * 2;              // jj even -> 4B aligned
        *(ushort2*)&poolh[ii * PSTRH + jj] = make_ushort2(f2h(v.x), f2h(v.z));
    }
    __syncthreads();
    float Dreg[32];
    #pragma unroll
    for (int k = 0; k < 32; ++k) {
        int j = jb + k;
        float s = h2f(poolh[i * PSTRH + j]) + h2f(poolh[j * PSTRH + i]);
        Dreg[k] = ((mword >> k) & 1) ? sp_softplus(dini + s) : 0.f;
    }
    __syncthreads();

    // ---------------- Pass C: stage ep.ch1 (fp16) -> Wreg ----------------
    #pragma unroll 4
    for (int k = 0; k < 16; ++k) {
        int e2 = t + k * 512;
        float4 v = ep4[e2];
        int ii = e2 >> 6, jj = (e2 & 63) * 2;
        *(ushort2*)&poolh[ii * PSTRH + jj] = make_ushort2(f2h(v.y), f2h(v.w));
    }
    __syncthreads();
    float Wreg[32];
    #pragma unroll
    for (int k = 0; k < 32; ++k) {
        int j = jb + k;
        float s = h2f(poolh[i * PSTRH + j]) + h2f(poolh[j * PSTRH + i]);
        Wreg[k] = ((mword >> k) & 1) ? sp_softplus(dini + s) : 0.f;
    }
    __syncthreads();           // staging dead; scrA/B/C (pool aliases) live

    // ---------------- Row sums of D^2 + grand mean ----------------
    float rp = 0.f;
    #pragma unroll
    for (int k = 0; k < 32; ++k) rp = fmaf(Dreg[k], Dreg[k], rp);
    scrA[t] = rp;
    __syncthreads();
    if (t < NN)
        r_s[t] = (scrA[t] + scrA[t + 128]) + (scrA[t + 256] + scrA[t + 384]);
    __syncthreads();
    float mt = r_s[lane] + r_s[lane + 64];
    #pragma unroll
    for (int off = 32; off; off >>= 1) mt += __shfl_xor(mt, off);

    const float Minv  = 1.0f / (float)(128 + s_cntM);
    const float invN  = 1.0f / (float)(1 + s_cntN0);
    const float cmean = mt * invN * invN;

    // ---------------- Gram matrix into registers ----------------
    const float ri = r_s[i];
    float Bg[32];
    #pragma unroll
    for (int k = 0; k < 32; ++k) {
        int j = jb + k;
        float dv = Dreg[k];
        float v  = -0.5f * (dv * dv - ri * invN - r_s[j] * invN + cmean);
        bool msk = ((mword >> k) & 1) || (i == j);
        Bg[k] = msk ? v : 0.f;
    }

    // ---------------- Power iteration: 3 ranks x 10 steps ----------------
    // v_{s+1} = A v_s / max(||v_s||,1e-3); u in LDS (float4 broadcasts);
    // norm via 2-wave butterfly published in nrm2[2].
    const float* ub = u_init  + (size_t)b * 384;
    const float* xb = x_noise + (size_t)b * 384;

    #pragma unroll 1
    for (int kx = 0; kx < 3; ++kx) {
        #pragma unroll 1
        for (int s = 0; s < 10; ++s) {
            if (t < NN) {   // waves 0,1 exactly
                float v = (s == 0) ? ub[t * 3 + kx]
                        : (scrA[t] + scrA[t + 128]) + (scrA[t + 256] + scrA[t + 384]);
                u_s[t] = v;
                float p2 = v * v;
                #pragma unroll
                for (int off = 32; off; off >>= 1) p2 += __shfl_xor(p2, off);
                if (lane == 0) nrm2[t >> 6] = p2;
            }
            __syncthreads();   // B1: u_s, nrm2 visible; scrA reads done
            float inv = rcpf(fmaxf(sqrtf(nrm2[0] + nrm2[1]), 0.001f));
            float a = 0.f;
            #pragma unroll
            for (int g = 0; g < 8; ++g) {
                float4 u4 = *(const float4*)&u_s[jb + 4 * g];
                a = fmaf(Bg[4*g    ], u4.x, a);
                a = fmaf(Bg[4*g + 1], u4.y, a);
                a = fmaf(Bg[4*g + 2], u4.z, a);
                a = fmaf(Bg[4*g + 3], u4.w, a);
            }
            scrA[t] = a * inv;
            __syncthreads();   // B2: new partials visible
        }
        // final v_10: magnitude matters (eig scaling)
        if (t < NN) {
            float v = (scrA[t] + scrA[t + 128]) + (scrA[t + 256] + scrA[t + 384]);
            u_s[t] = v;
            float p2 = v * v;
            #pragma unroll
            for (int off = 32; off; off >>= 1) p2 += __shfl_xor(p2, off);
            if (lane == 0) nrm2[t >> 6] = p2;
        }
        __syncthreads();       // B3
        float e2  = nrm2[0] + nrm2[1];
        float esc = rsqf(sqrtf(e2 + 0.01f));      // (eig_sq+0.01)^-0.25
        float c   = u_s[i] * esc * esc;           // row-i factor (scaled^2)
        #pragma unroll
        for (int g = 0; g < 8; ++g) {
            float4 u4 = *(const float4*)&u_s[jb + 4 * g];
            Bg[4*g    ] = fmaf(-c, u4.x, Bg[4*g    ]);
            Bg[4*g + 1] = fmaf(-c, u4.y, Bg[4*g + 1]);
            Bg[4*g + 2] = fmaf(-c, u4.z, Bg[4*g + 2]);
            Bg[4*g + 3] = fmaf(-c, u4.w, Bg[4*g + 3]);
        }
        if (t < NN) {
            float* Xc = (kx == 0) ? Xx : (kx == 1) ? Xy : Xz;
            Xc[t] = u_s[t] * esc + xb[t * 3 + kx];   // x0 = lowrank + noise
        }
        __syncthreads();       // B4: u_s reads done before next rank's writes
    }

    // ---------------- Gradient descent: 10 steps ----------------
    // dx_i = (0.4/M) * sum_j W_ij (D_ij - DX_ij)/DX_ij * (x_i - x_j)
    const float stepc = 0.4f * Minv;
    #pragma unroll 1
    for (int st = 0; st < 10; ++st) {
        float xix = Xx[i], xiy = Xy[i], xiz = Xz[i];
        float gx = 0.f, gy = 0.f, gz = 0.f;
        #pragma unroll
        for (int g = 0; g < 8; ++g) {
            float4 vx = *(const float4*)&Xx[jb + 4 * g];   // wave-uniform b128
            float4 vy = *(const float4*)&Xy[jb + 4 * g];
            float4 vz = *(const float4*)&Xz[jb + 4 * g];
            #pragma unroll
            for (int c = 0; c < 4; ++c) {
                int k = 4 * g + c;
                float jx = (c == 0) ? vx.x : (c == 1) ? vx.y : (c == 2) ? vx.z : vx.w;
                float jy = (c == 0) ? vy.x : (c == 1) ? vy.y : (c == 2) ? vy.z : vy.w;
                float jz = (c == 0) ? vz.x : (c == 1) ? vz.y : (c == 2) ? vz.z : vz.w;
                float dx = xix - jx, dy = xiy - jy, dz = xiz - jz;
                float d2 = fmaf(dx, dx, fmaf(dy, dy, fmaf(dz, dz, 0.01f)));
                float rv = rsqf(d2);                      // 1/DX
                float c2 = fmaf(Dreg[k] * rv, Wreg[k], -Wreg[k]);  // W*(D/DX-1)
                gx = fmaf(c2, dx, gx);
                gy = fmaf(c2, dy, gy);
                gz = fmaf(c2, dz, gz);
            }
        }
        scrA[t] = gx; scrB[t] = gy; scrC[t] = gz;
        __syncthreads();
        if (t < NN) {
            float sx = (scrA[t] + scrA[t + 128]) + (scrA[t + 256] + scrA[t + 384]);
            float sy = (scrB[t] + scrB[t + 128]) + (scrB[t + 256] + scrB[t + 384]);
            float sz = (scrC[t] + scrC[t + 128]) + (scrC[t + 256] + scrC[t + 384]);
            float dxv = sx * stepc, dyv = sy * stepc, dzv = sz * stepc;
            float spd = sqrtf(fmaf(dxv, dxv, fmaf(dyv, dyv, fmaf(dzv, dzv, 0.001f))));
            float alpha = 0.1f + 4.9f * (float)(10 - st) * 0.1f;
            // fast tanh: (e-1)/(e+1), e = exp(2z), z clamped
            float z  = fminf(spd * rcpf(alpha), 20.0f);
            float e  = __builtin_amdgcn_exp2f(z * 2.88539008f);
            float th = (e - 1.0f) * rcpf(e + 1.0f);
            float scl = alpha * th * rcpf(spd);
            Xx[t] = fmaf(dxv, scl, Xx[t]);
            Xy[t] = fmaf(dyv, scl, Xy[t]);
            Xz[t] = fmaf(dzv, scl, Xz[t]);
        }
        __syncthreads();
    }

    // ---------------- Output: mask * distances(X), float4 stores ----------------
    float* ob = out + (size_t)b * 16384;
    #pragma unroll
    for (int k = 0; k < 8; ++k) {
        int e4 = t + k * 512;
        int ii = e4 >> 5, jjb = (e4 & 31) * 4;
        float xix = Xx[ii], xiy = Xy[ii], xiz = Xz[ii];
        float4 vx = *(const float4*)&Xx[jjb];
        float4 vy = *(const float4*)&Xy[jjb];
        float4 vz = *(const float4*)&Xz[jjb];
        unsigned mw = maskb[ii * 4 + (jjb >> 5)];
        float4 o;
        float dx, dy, dz, d2;
        dx = xix - vx.x; dy = xiy - vy.x; dz = xiz - vz.x;
        d2 = fmaf(dx, dx, fmaf(dy, dy, fmaf(dz, dz, 0.01f)));
        o.x = ((mw >> ((jjb + 0) & 31)) & 1) ? sqrtf(d2) : 0.f;
        dx = xix - vx.y; dy = xiy - vy.y; dz = xiz - vz.y;
        d2 = fmaf(dx, dx, fmaf(dy, dy, fmaf(dz, dz, 0.01f)));
        o.y = ((mw >> ((jjb + 1) & 31)) & 1) ? sqrtf(d2) : 0.f;
        dx = xix - vx.z; dy = xiy - vy.z; dz = xiz - vz.z;
        d2 = fmaf(dx, dx, fmaf(dy, dy, fmaf(dz, dz, 0.01f)));
        o.z = ((mw >> ((jjb + 2) & 31)) & 1) ? sqrtf(d2) : 0.f;
        dx = xix - vx.w; dy = xiy - vy.w; dz = xiz - vz.w;
        d2 = fmaf(dx, dx, fmaf(dy, dy, fmaf(dz, dz, 0.01f)));
        o.w = ((mw >> ((jjb + 3) & 31)) & 1) ? sqrtf(d2) : 0.f;
        ((float4*)ob)[e4] = o;
    }
}

extern "C" void kernel_launch(void* const* d_in, const int* in_sizes, int n_in,
                              void* d_out, int out_size, void* d_ws, size_t ws_size,
                              hipStream_t stream) {
    const float* edge_pred = (const float*)d_in[0];
    const int*   adj       = (const int*)  d_in[1];
    const float* dinit     = (const float*)d_in[2];
    const float* u_init    = (const float*)d_in[3];
    const float* x_noise   = (const float*)d_in[4];
    float*       out       = (float*)d_out;

    ts_gcn_kernel<<<512, NTH, 0, stream>>>(edge_pred, adj, dinit, u_init, x_noise, out);
}